// Round 5
// baseline (341.303 us; speedup 1.0000x reference)
//
#include <hip/hip_runtime.h>
#include <hip/hip_bf16.h>

#define NB 16
#define TT 2048
#define CC 384

typedef short bf16x8 __attribute__((ext_vector_type(8)));
typedef float f32x4 __attribute__((ext_vector_type(4)));

static __device__ __forceinline__ short f2bf(float f) {
  union { __hip_bfloat16 h; short s; } u;
  u.h = __float2bfloat16(f);
  return u.s;
}

// C^-0.5 * log2(e): folded into Q at projection time (attn works in exp2 domain)
#define QSC (0.051031036307982884f * 1.4426950408889634f)

// ---------------------------------------------------------------------------
// W[3] (fp32 [C][H]) -> Wbt (bf16 [3][n=H][k=C])  (transposed for LDS staging)
// ---------------------------------------------------------------------------
__global__ __launch_bounds__(384)
void conv_wt(const float* __restrict__ Wq, const float* __restrict__ Wk,
             const float* __restrict__ Wv, short* __restrict__ Wbt) {
  const int w = blockIdx.x / CC;
  const int n = blockIdx.x % CC;
  const int k = threadIdx.x;
  const float* W = (w == 0) ? Wq : (w == 1) ? Wk : Wv;
  Wbt[((size_t)w * CC + n) * CC + k] = f2bf(W[(size_t)k * CC + n]);
}

// ---------------------------------------------------------------------------
// x (fp32 [B*T*C]) -> xb (bf16), one pass.
// ---------------------------------------------------------------------------
__global__ __launch_bounds__(256)
void xconv(const float* __restrict__ x, short* __restrict__ xb) {
  const int i = (blockIdx.x * 256 + threadIdx.x) * 8;
  const float4 a = *(const float4*)(x + i);
  const float4 c = *(const float4*)(x + i + 4);
  bf16x8 r;
  r[0] = f2bf(a.x); r[1] = f2bf(a.y); r[2] = f2bf(a.z); r[3] = f2bf(a.w);
  r[4] = f2bf(c.x); r[5] = f2bf(c.y); r[6] = f2bf(c.z); r[7] = f2bf(c.w);
  *(bf16x8*)(xb + i) = r;
}

// ---------------------------------------------------------------------------
// Fused QKV projection GEMM: [32768 x 384] bf16 x [384 x 1152] bf16.
// NEW: BK=64 (6 K-iters of 32 MFMA, was 12x16) -> half the barriers/waits,
// 2x compute per sync window. 64 KB LDS double-buffer, global_load_lds 16B,
// counted vmcnt(8). XOR swizzle slot^=(row&7) on pre-swizzled global source
// keeps 128B-row reads 2-way bank-free.
// ---------------------------------------------------------------------------
__global__ __launch_bounds__(256, 2)
void proj_gemm(const short* __restrict__ xb, const short* __restrict__ Wbt,
               short* __restrict__ Q, short* __restrict__ K,
               short* __restrict__ Vt) {
  __shared__ char smem[65536];
  // A0 [0,16K) A1 [16K,32K) B0 [32K,48K) B1 [48K,64K); epilogue Es reuses.
  short* Es = (short*)smem;              // epilogue [128][136]

  const int mt = blockIdx.x & 255;
  const int nt = blockIdx.x >> 8;        // 0..8
  const int wsel = nt / 3;               // 0=Q,1=K,2=V
  const int nc0 = (nt % 3) * 128;
  const int tid = threadIdx.x;
  const int wave = tid >> 6, lane = tid & 63;
  const int l15 = lane & 15, quad = lane >> 4;
  const int wm = (wave & 1) * 64, wn = (wave >> 1) * 64;

  const short* Ab = xb + (size_t)mt * 128 * CC;
  const short* Bb = Wbt + ((size_t)wsel * CC + nc0) * CC;

  // per-lane pre-swizzled source offsets (elements) for the 4 issues/wave
  // tile: [128 rows][64 k-elems] = 16 KB, rows 128 B, 8 16B slots/row
  int aoff[4];
  #pragma unroll
  for (int j = 0; j < 4; ++j) {
    const int lin = wave * 4096 + j * 1024 + lane * 16;  // byte in 16K tile
    const int r = lin >> 7;                              // row
    const int s = (lin >> 4) & 7;                        // 16B slot
    aoff[j] = r * CC + ((s ^ (r & 7)) << 3);             // inverse swizzle
  }

  f32x4 acc[16];
  #pragma unroll
  for (int i = 0; i < 16; ++i) acc[i] = f32x4{0.f, 0.f, 0.f, 0.f};

  // prologue: stage kt 0 -> buf0, kt 1 -> buf1 (8 issues/wave per kt)
  #pragma unroll
  for (int pc = 0; pc < 2; ++pc) {
    #pragma unroll
    for (int j = 0; j < 4; ++j)
      __builtin_amdgcn_global_load_lds(
          (const __attribute__((address_space(1))) void*)(Ab + pc * 64 + aoff[j]),
          (__attribute__((address_space(3))) void*)(smem + pc * 16384 + wave * 4096 + j * 1024), 16, 0, 0);
    #pragma unroll
    for (int j = 0; j < 4; ++j)
      __builtin_amdgcn_global_load_lds(
          (const __attribute__((address_space(1))) void*)(Bb + pc * 64 + aoff[j]),
          (__attribute__((address_space(3))) void*)(smem + 32768 + pc * 16384 + wave * 4096 + j * 1024), 16, 0, 0);
  }

  for (int kt = 0; kt < 6; ++kt) {
    const int kb = kt & 1;
    if (kt == 5) {
      asm volatile("s_waitcnt vmcnt(0)" ::: "memory");
    } else {
      asm volatile("s_waitcnt vmcnt(8)" ::: "memory");
    }
    __builtin_amdgcn_s_barrier();
    __builtin_amdgcn_sched_barrier(0);

    const char* As = smem + kb * 16384;
    const char* Bs = smem + 32768 + kb * 16384;
    #pragma unroll
    for (int ks = 0; ks < 2; ++ks) {
      bf16x8 af[4], bf[4];
      #pragma unroll
      for (int i = 0; i < 4; ++i) {
        const int ar = wm + i * 16 + l15;
        const int br = wn + i * 16 + l15;
        af[i] = *(const bf16x8*)(As + ar * 128 + (((ks * 4 + quad) ^ (ar & 7)) << 4));
        bf[i] = *(const bf16x8*)(Bs + br * 128 + (((ks * 4 + quad) ^ (br & 7)) << 4));
      }
      #pragma unroll
      for (int i = 0; i < 4; ++i)
        #pragma unroll
        for (int j = 0; j < 4; ++j)
          acc[i * 4 + j] =
              __builtin_amdgcn_mfma_f32_16x16x32_bf16(af[i], bf[j], acc[i * 4 + j], 0, 0, 0);
    }

    __builtin_amdgcn_sched_barrier(0);
    __builtin_amdgcn_s_barrier();
    if (kt + 2 < 6) {
      const int k0 = (kt + 2) * 64;
      #pragma unroll
      for (int j = 0; j < 4; ++j)
        __builtin_amdgcn_global_load_lds(
            (const __attribute__((address_space(1))) void*)(Ab + k0 + aoff[j]),
            (__attribute__((address_space(3))) void*)(smem + kb * 16384 + wave * 4096 + j * 1024), 16, 0, 0);
      #pragma unroll
      for (int j = 0; j < 4; ++j)
        __builtin_amdgcn_global_load_lds(
            (const __attribute__((address_space(1))) void*)(Bb + k0 + aoff[j]),
            (__attribute__((address_space(3))) void*)(smem + 32768 + kb * 16384 + wave * 4096 + j * 1024), 16, 0, 0);
    }
  }

  if (nt < 6) {
    short* O = (nt < 3) ? Q : K;
    const float sc = (nt < 3) ? QSC : 1.0f;
    #pragma unroll
    for (int i = 0; i < 4; ++i)
      #pragma unroll
      for (int j = 0; j < 4; ++j) {
        const f32x4 a = acc[i * 4 + j];
        const int r0 = mt * 128 + wm + i * 16 + quad * 4;
        const int c = nc0 + wn + j * 16 + l15;
        #pragma unroll
        for (int r = 0; r < 4; ++r) O[(size_t)(r0 + r) * CC + c] = f2bf(a[r] * sc);
      }
  } else {
    __syncthreads();                     // done with staging; reuse as Es
    #pragma unroll
    for (int i = 0; i < 4; ++i)
      #pragma unroll
      for (int j = 0; j < 4; ++j) {
        const f32x4 a = acc[i * 4 + j];
        const int dl = wn + j * 16 + l15;       // local col (d)
        const int ml = wm + i * 16 + quad * 4;  // local row (t)
        short4 p4;
        p4.x = f2bf(a[0]); p4.y = f2bf(a[1]); p4.z = f2bf(a[2]); p4.w = f2bf(a[3]);
        *(short4*)(Es + (size_t)dl * 136 + ml) = p4;
      }
    __syncthreads();
    const int d0 = (nt - 6) * 128;
    const int b = mt >> 4, t0 = (mt & 15) * 128;
    const int dr = tid >> 1, hf = tid & 1;
    const short* src = Es + (size_t)dr * 136 + hf * 64;
    short* dst = Vt + ((size_t)b * CC + d0 + dr) * TT + t0 + hf * 64;
    #pragma unroll
    for (int c = 0; c < 8; ++c)
      *(bf16x8*)(dst + c * 8) = *(const bf16x8*)(src + c * 8);
  }
}

// ===========================================================================
// Flash attention, causal, 64q/4-wave blocks, 32-key chunks, async
// global_load_lds phase-shifted staging (round-2 proven core).
//
// attn_split (parity version): role A = EVEN chunks, role B = ODD chunks of
// BOTH tiles (H=31-j first, then L=j). Each role = (32-j)+(j+1) = 33 chunks:
// perfect balance AND temporal locality: co-resident pair (blk, blk+256) =
// A/B of the same (b,j) reading adjacent chunks simultaneously; all blocks
// in H-phase read chunk 2w/2w+1 at wall w -> L2 sharing restored (round-4's
// balanced-range split pushed FETCH 37->260 MB; this brings it back).
// Every tile = 2 partials: A's (unnormalized, f32) parked in out, B's in ws;
// combine merges all 512 tiles. Fallback to attn_plain when ws too small.
// ===========================================================================

#define ATTN_PRELUDE                                                          \
  __shared__ char sm[54272];                                                  \
  char* KsS = sm;                                                             \
  char* VsS = sm + 24576;                                                     \
  const int tid = threadIdx.x;                                                \
  const int wave = tid >> 6, lane = tid & 63;                                 \
  const int l15 = lane & 15, quad = lane >> 4;                                \
  short* pw = (short*)(sm + 49152) + wave * 640;                              \
  bf16x8 onesf;                                                               \
  _Pragma("unroll")                                                           \
  for (int i = 0; i < 8; ++i) onesf[i] = (short)0x3F80;                       \
  int koff[6], voff[6];                                                       \
  _Pragma("unroll")                                                           \
  for (int j = 0; j < 6; ++j) {                                               \
    const int lin = wave * 6144 + j * 1024 + lane * 16;                       \
    const int kr = lin / 768;                                                 \
    const int ksl = (lin - kr * 768) >> 4;                                    \
    koff[j] = kr * 768 + ((ksl ^ (kr & 7)) << 4);                             \
    const int vr = lin >> 6;                                                  \
    const int vsl = (lin >> 4) & 3;                                           \
    voff[j] = vr * 4096 + (((vsl - (vr >> 2)) & 3) << 4);                     \
  }                                                                           \
  char* KsW = KsS + wave * 6144;                                              \
  char* VsW = VsS + wave * 6144;

#define STAGE_K(ck)                                                           \
  do {                                                                        \
    const size_t kby_ = (size_t)(ck) * 24576;                                 \
    _Pragma("unroll")                                                         \
    for (int j5 = 0; j5 < 6; ++j5)                                            \
      __builtin_amdgcn_global_load_lds(                                       \
          (const __attribute__((address_space(1))) void*)(kbB + kby_ + koff[j5]), \
          (__attribute__((address_space(3))) void*)(KsW + j5 * 1024), 16, 0, 0);  \
  } while (0)

#define STAGE_V(ck)                                                           \
  do {                                                                        \
    const size_t vby_ = (size_t)(ck) * 64;                                    \
    _Pragma("unroll")                                                         \
    for (int j5 = 0; j5 < 6; ++j5)                                            \
      __builtin_amdgcn_global_load_lds(                                       \
          (const __attribute__((address_space(1))) void*)(vtB + vby_ + voff[j5]), \
          (__attribute__((address_space(3))) void*)(VsW + j5 * 1024), 16, 0, 0);  \
  } while (0)

__global__ __launch_bounds__(256, 2)
void attn_plain(const short* __restrict__ Q, const short* __restrict__ K,
                const short* __restrict__ Vt, float* __restrict__ out) {
  ATTN_PRELUDE
  const int blk = blockIdx.x;
  const int qt = 31 - (blk >> 4);
  const int b  = blk & 15;
  const int q0 = qt * 64 + wave * 16;

  bf16x8 qf[12];
  const short* qp = Q + ((size_t)b * TT + q0 + l15) * CC + quad * 8;
  #pragma unroll
  for (int ks = 0; ks < 12; ++ks) qf[ks] = *(const bf16x8*)(qp + ks * 32);

  f32x4 o[24];
  #pragma unroll
  for (int n = 0; n < 24; ++n) o[n] = f32x4{0.f, 0.f, 0.f, 0.f};
  f32x4 lsum = f32x4{0.f, 0.f, 0.f, 0.f};
  float m[4];
  #pragma unroll
  for (int r = 0; r < 4; ++r) m[r] = -INFINITY;

  const char* kbB = (const char*)(K + (size_t)b * TT * CC);
  const char* vtB = (const char*)(Vt + (size_t)b * CC * TT);
  const int nchunk = qt * 2 + 2;

  STAGE_K(0);
  STAGE_V(0);

  for (int kc = 0; kc < nchunk; ++kc) {
    const int k0 = kc * 32;
    asm volatile("s_waitcnt vmcnt(6)" ::: "memory");
    __builtin_amdgcn_s_barrier();
    __builtin_amdgcn_sched_barrier(0);

    f32x4 s0 = f32x4{0.f, 0.f, 0.f, 0.f};
    f32x4 s1 = f32x4{0.f, 0.f, 0.f, 0.f};
    const bool active = (k0 <= q0 + 15);
    if (active) {
      #pragma unroll
      for (int ks = 0; ks < 12; ++ks) {
        const int sl = (ks * 4 + quad) ^ (l15 & 7);
        const bf16x8 b0 = *(const bf16x8*)(KsS + l15 * 768 + (sl << 4));
        const bf16x8 b1 = *(const bf16x8*)(KsS + (16 + l15) * 768 + (sl << 4));
        s0 = __builtin_amdgcn_mfma_f32_16x16x32_bf16(qf[ks], b0, s0, 0, 0, 0);
        s1 = __builtin_amdgcn_mfma_f32_16x16x32_bf16(qf[ks], b1, s1, 0, 0, 0);
      }
    }
    __builtin_amdgcn_sched_barrier(0);
    __builtin_amdgcn_s_barrier();
    { const int kn = (kc + 1 < nchunk) ? (kc + 1) : kc; STAGE_K(kn); }
    asm volatile("s_waitcnt vmcnt(6)" ::: "memory");
    __builtin_amdgcn_s_barrier();
    __builtin_amdgcn_sched_barrier(0);

    if (active) {
      const bool domask = (k0 + 31 > q0);
      float mx[4];
      #pragma unroll
      for (int r = 0; r < 4; ++r) {
        float a = s0[r], c = s1[r];
        if (domask) {
          const int qg = q0 + quad * 4 + r;
          if (k0 + l15 > qg)      a = -INFINITY;
          if (k0 + 16 + l15 > qg) c = -INFINITY;
        }
        s0[r] = a; s1[r] = c;
        float v = fmaxf(a, c);
        v = fmaxf(v, __shfl_xor(v, 1));
        v = fmaxf(v, __shfl_xor(v, 2));
        v = fmaxf(v, __shfl_xor(v, 4));
        v = fmaxf(v, __shfl_xor(v, 8));
        mx[r] = v;
      }
      float alpha[4];
      #pragma unroll
      for (int r = 0; r < 4; ++r) {
        const float mn = fmaxf(m[r], mx[r]);
        alpha[r] = exp2f(m[r] - mn);
        m[r] = mn;
        s0[r] = exp2f(s0[r] - mn);
        s1[r] = exp2f(s1[r] - mn);
      }
      const bool need = (alpha[0] < 1.f) | (alpha[1] < 1.f) |
                        (alpha[2] < 1.f) | (alpha[3] < 1.f);
      if (__any(need)) {
        #pragma unroll
        for (int r = 0; r < 4; ++r) lsum[r] *= alpha[r];
        #pragma unroll
        for (int n = 0; n < 24; ++n) {
          #pragma unroll
          for (int r = 0; r < 4; ++r) o[n][r] *= alpha[r];
        }
      }
      #pragma unroll
      for (int r = 0; r < 4; ++r) {
        pw[(quad * 4 + r) * 40 + l15]      = f2bf(s0[r]);
        pw[(quad * 4 + r) * 40 + 16 + l15] = f2bf(s1[r]);
      }
      const bf16x8 pf = *(const bf16x8*)(pw + l15 * 40 + quad * 8);
      lsum = __builtin_amdgcn_mfma_f32_16x16x32_bf16(pf, onesf, lsum, 0, 0, 0);
      #pragma unroll
      for (int n = 0; n < 24; ++n) {
        const int vrow = n * 16 + l15;
        const bf16x8 vf = *(const bf16x8*)(VsS + vrow * 64 + (((quad + (vrow >> 2)) & 3) << 4));
        o[n] = __builtin_amdgcn_mfma_f32_16x16x32_bf16(pf, vf, o[n], 0, 0, 0);
      }
    }
    __builtin_amdgcn_sched_barrier(0);
    __builtin_amdgcn_s_barrier();
    { const int kn = (kc + 1 < nchunk) ? (kc + 1) : kc; STAGE_V(kn); }
  }

  float linv[4];
  #pragma unroll
  for (int r = 0; r < 4; ++r) linv[r] = 1.f / lsum[r];
  float* ob = out + ((size_t)b * TT + q0) * CC;
  #pragma unroll
  for (int n = 0; n < 24; ++n) {
    #pragma unroll
    for (int r = 0; r < 4; ++r) {
      ob[(size_t)(quad * 4 + r) * CC + n * 16 + l15] = o[n][r] * linv[r];
    }
  }
}

__global__ __launch_bounds__(256, 2)
void attn_split(const short* __restrict__ Q, const short* __restrict__ K,
                const short* __restrict__ Vt, float* __restrict__ out,
                float* __restrict__ OB, float* __restrict__ ML) {
  ATTN_PRELUDE
  const int blk = blockIdx.x;
  const int b = blk & 15;                   // XCD = b%8
  const int s = blk >> 4;                   // 0..31
  const int j = s & 15;
  const int role = s >> 4;                  // 0: even chunks, 1: odd chunks

  const char* kbB = (const char*)(K + (size_t)b * TT * CC);
  const char* vtB = (const char*)(Vt + (size_t)b * CC * TT);

  #pragma unroll 1
  for (int ph = 0; ph < 2; ++ph) {
    const int qt = ph ? j : (31 - j);       // H first (aligned across pairs)
    const int tile = b * 32 + qt;
    const int nchunk = qt * 2 + 2;
    const int q0 = qt * 64 + wave * 16;

    bf16x8 qf[12];
    const short* qp = Q + ((size_t)b * TT + q0 + l15) * CC + quad * 8;
    #pragma unroll
    for (int ks = 0; ks < 12; ++ks) qf[ks] = *(const bf16x8*)(qp + ks * 32);
    // drain q loads + previous phase's trailing stages -> clean vmcnt base
    asm volatile("s_waitcnt vmcnt(0)" ::: "memory");

    f32x4 o[24];
    #pragma unroll
    for (int n = 0; n < 24; ++n) o[n] = f32x4{0.f, 0.f, 0.f, 0.f};
    f32x4 lsum = f32x4{0.f, 0.f, 0.f, 0.f};
    float m[4];
    #pragma unroll
    for (int r = 0; r < 4; ++r) m[r] = -INFINITY;

    STAGE_K(role);
    STAGE_V(role);

    #pragma unroll 1
    for (int kc = role; kc < nchunk; kc += 2) {
      const int k0 = kc * 32;
      asm volatile("s_waitcnt vmcnt(6)" ::: "memory");
      __builtin_amdgcn_s_barrier();
      __builtin_amdgcn_sched_barrier(0);

      f32x4 s0 = f32x4{0.f, 0.f, 0.f, 0.f};
      f32x4 s1 = f32x4{0.f, 0.f, 0.f, 0.f};
      const bool active = (k0 <= q0 + 15);
      if (active) {
        #pragma unroll
        for (int ks = 0; ks < 12; ++ks) {
          const int sl = (ks * 4 + quad) ^ (l15 & 7);
          const bf16x8 b0 = *(const bf16x8*)(KsS + l15 * 768 + (sl << 4));
          const bf16x8 b1 = *(const bf16x8*)(KsS + (16 + l15) * 768 + (sl << 4));
          s0 = __builtin_amdgcn_mfma_f32_16x16x32_bf16(qf[ks], b0, s0, 0, 0, 0);
          s1 = __builtin_amdgcn_mfma_f32_16x16x32_bf16(qf[ks], b1, s1, 0, 0, 0);
        }
      }
      __builtin_amdgcn_sched_barrier(0);
      __builtin_amdgcn_s_barrier();
      { const int kn = (kc + 2 < nchunk) ? (kc + 2) : kc; STAGE_K(kn); }
      asm volatile("s_waitcnt vmcnt(6)" ::: "memory");
      __builtin_amdgcn_s_barrier();
      __builtin_amdgcn_sched_barrier(0);

      if (active) {
        const bool domask = (k0 + 31 > q0);
        float mx[4];
        #pragma unroll
        for (int r = 0; r < 4; ++r) {
          float a = s0[r], c = s1[r];
          if (domask) {
            const int qg = q0 + quad * 4 + r;
            if (k0 + l15 > qg)      a = -INFINITY;
            if (k0 + 16 + l15 > qg) c = -INFINITY;
          }
          s0[r] = a; s1[r] = c;
          float v = fmaxf(a, c);
          v = fmaxf(v, __shfl_xor(v, 1));
          v = fmaxf(v, __shfl_xor(v, 2));
          v = fmaxf(v, __shfl_xor(v, 4));
          v = fmaxf(v, __shfl_xor(v, 8));
          mx[r] = v;
        }
        float alpha[4];
        #pragma unroll
        for (int r = 0; r < 4; ++r) {
          const float mn = fmaxf(m[r], mx[r]);
          alpha[r] = exp2f(m[r] - mn);
          m[r] = mn;
          s0[r] = exp2f(s0[r] - mn);
          s1[r] = exp2f(s1[r] - mn);
        }
        const bool need = (alpha[0] < 1.f) | (alpha[1] < 1.f) |
                          (alpha[2] < 1.f) | (alpha[3] < 1.f);
        if (__any(need)) {
          #pragma unroll
          for (int r = 0; r < 4; ++r) lsum[r] *= alpha[r];
          #pragma unroll
          for (int n = 0; n < 24; ++n) {
            #pragma unroll
            for (int r = 0; r < 4; ++r) o[n][r] *= alpha[r];
          }
        }
        #pragma unroll
        for (int r = 0; r < 4; ++r) {
          pw[(quad * 4 + r) * 40 + l15]      = f2bf(s0[r]);
          pw[(quad * 4 + r) * 40 + 16 + l15] = f2bf(s1[r]);
        }
        const bf16x8 pf = *(const bf16x8*)(pw + l15 * 40 + quad * 8);
        lsum = __builtin_amdgcn_mfma_f32_16x16x32_bf16(pf, onesf, lsum, 0, 0, 0);
        #pragma unroll
        for (int n = 0; n < 24; ++n) {
          const int vrow = n * 16 + l15;
          const bf16x8 vf = *(const bf16x8*)(VsS + vrow * 64 + (((quad + (vrow >> 2)) & 3) << 4));
          o[n] = __builtin_amdgcn_mfma_f32_16x16x32_bf16(pf, vf, o[n], 0, 0, 0);
        }
      }
      __builtin_amdgcn_sched_barrier(0);
      __builtin_amdgcn_s_barrier();
      { const int kn = (kc + 2 < nchunk) ? (kc + 2) : kc; STAGE_V(kn); }
    }

    // ---- partial epilogue: unnormalized O + (m,l) per row
    float* ob = (role == 0)
        ? out + ((size_t)b * TT + q0) * CC
        : OB + (size_t)tile * 24576 + (size_t)(wave * 16) * CC;
    #pragma unroll
    for (int n = 0; n < 24; ++n) {
      #pragma unroll
      for (int r = 0; r < 4; ++r)
        ob[(size_t)(quad * 4 + r) * CC + n * 16 + l15] = o[n][r];
    }
    if (l15 == 0) {
      float* pml = ML + (size_t)tile * 256 + role * 128;
      #pragma unroll
      for (int r = 0; r < 4; ++r) {
        pml[(wave * 16 + quad * 4 + r) * 2]     = m[r];
        pml[(wave * 16 + quad * 4 + r) * 2 + 1] = lsum[r];
      }
    }
  }
}

// ---------------------------------------------------------------------------
// Merge partial A (in out) with partial B (in ws) for all 512 tiles.
// exp2f(-inf - finite) = 0 handles empty-B rows (l=0, m=-inf) safely;
// partial A always contains chunk 0 -> mA finite, lA > 0.
// ---------------------------------------------------------------------------
__global__ __launch_bounds__(256)
void combine(float* __restrict__ out, const float* __restrict__ OB,
             const float* __restrict__ ML) {
  const int t = blockIdx.x;
  const int b = t >> 5, qt = t & 31;
  const int row = threadIdx.x >> 2, seg = threadIdx.x & 3;
  const float* ml = ML + (size_t)t * 256;
  const float mA = ml[row * 2],       lA = ml[row * 2 + 1];
  const float mB = ml[128 + row * 2], lB = ml[128 + row * 2 + 1];
  const float mF = fmaxf(mA, mB);
  const float sA = exp2f(mA - mF), sB = exp2f(mB - mF);
  const float inv = 1.f / (lA * sA + lB * sB);
  const float wA = sA * inv, wB = sB * inv;
  float* pa = out + ((size_t)b * TT + qt * 64 + row) * CC + seg * 96;
  const float* pb = OB + (size_t)t * 24576 + (size_t)row * CC + seg * 96;
  #pragma unroll
  for (int c = 0; c < 24; ++c) {
    float4 a = *(float4*)(pa + c * 4);
    const float4 bb = *(const float4*)(pb + c * 4);
    a.x = a.x * wA + bb.x * wB;
    a.y = a.y * wA + bb.y * wB;
    a.z = a.z * wA + bb.z * wB;
    a.w = a.w * wA + bb.w * wB;
    *(float4*)(pa + c * 4) = a;
  }
}

extern "C" void kernel_launch(void* const* d_in, const int* in_sizes, int n_in,
                              void* d_out, int out_size, void* d_ws, size_t ws_size,
                              hipStream_t stream) {
  const float* x  = (const float*)d_in[0];
  const float* Wq = (const float*)d_in[1];
  const float* Wk = (const float*)d_in[2];
  const float* Wv = (const float*)d_in[3];
  float* out = (float*)d_out;

  const size_t QS = (size_t)NB * TT * CC;     // 12.58M elems
  short* Qs = (short*)d_ws;
  short* Ks = Qs + QS;
  short* Vt = Ks + QS;                        // 75,497,472 B

  const size_t base = QS * 3 * 2;
  float* OB = (float*)((char*)d_ws + base);             // 50,331,648 B
  float* ML = (float*)((char*)d_ws + base + 50331648);  //    524,288 B
  const bool split = ws_size >= base + 50331648 + 524288;

  // bf16 W^T (0.9MB) and bf16 x (25.2MB) staged in d_out until attn
  short* Wbt = (short*)d_out;
  short* xb  = (short*)((char*)d_out + 1048576);

  hipLaunchKernelGGL(conv_wt, dim3(3 * CC), dim3(CC), 0, stream, Wq, Wk, Wv, Wbt);
  hipLaunchKernelGGL(xconv, dim3(6144), dim3(256), 0, stream, x, xb);
  hipLaunchKernelGGL(proj_gemm, dim3(256 * 9), dim3(256), 0, stream,
                     xb, Wbt, Qs, Ks, Vt);
  if (split) {
    hipLaunchKernelGGL(attn_split, dim3(512), dim3(256), 0, stream,
                       Qs, Ks, Vt, out, OB, ML);
    hipLaunchKernelGGL(combine, dim3(512), dim3(256), 0, stream, out, OB, ML);
  } else {
    hipLaunchKernelGGL(attn_plain, dim3(512), dim3(256), 0, stream,
                       Qs, Ks, Vt, out);
  }
}

// Round 6
// 303.685 us; speedup vs baseline: 1.1239x; 1.1239x over previous
//
#include <hip/hip_runtime.h>
#include <hip/hip_bf16.h>

#define NB 16
#define TT 2048
#define CC 384

typedef short bf16x8 __attribute__((ext_vector_type(8)));
typedef float f32x4 __attribute__((ext_vector_type(4)));

static __device__ __forceinline__ short f2bf(float f) {
  union { __hip_bfloat16 h; short s; } u;
  u.h = __float2bfloat16(f);
  return u.s;
}

// C^-0.5 * log2(e): folded into Q at projection time (attn works in exp2 domain)
#define QSC (0.051031036307982884f * 1.4426950408889634f)

// ---------------------------------------------------------------------------
// W[3] (fp32 [C][H]) -> Wbt (bf16 [3][n=H][k=C])  (transposed for LDS staging)
// ---------------------------------------------------------------------------
__global__ __launch_bounds__(384)
void conv_wt(const float* __restrict__ Wq, const float* __restrict__ Wk,
             const float* __restrict__ Wv, short* __restrict__ Wbt) {
  const int w = blockIdx.x / CC;
  const int n = blockIdx.x % CC;
  const int k = threadIdx.x;
  const float* W = (w == 0) ? Wq : (w == 1) ? Wk : Wv;
  Wbt[((size_t)w * CC + n) * CC + k] = f2bf(W[(size_t)k * CC + n]);
}

// ---------------------------------------------------------------------------
// x (fp32 [B*T*C]) -> xb (bf16), one pass.
// ---------------------------------------------------------------------------
__global__ __launch_bounds__(256)
void xconv(const float* __restrict__ x, short* __restrict__ xb) {
  const int i = (blockIdx.x * 256 + threadIdx.x) * 8;
  const float4 a = *(const float4*)(x + i);
  const float4 c = *(const float4*)(x + i + 4);
  bf16x8 r;
  r[0] = f2bf(a.x); r[1] = f2bf(a.y); r[2] = f2bf(a.z); r[3] = f2bf(a.w);
  r[4] = f2bf(c.x); r[5] = f2bf(c.y); r[6] = f2bf(c.z); r[7] = f2bf(c.w);
  *(bf16x8*)(xb + i) = r;
}

// ---------------------------------------------------------------------------
// Fused QKV projection GEMM: [32768 x 384] bf16 x [384 x 1152] bf16.
// BK=64 (6 K-iters of 32 MFMA), 64 KB LDS double-buffer, global_load_lds 16B,
// counted vmcnt(8), XOR swizzle slot^=(row&7) (pre-swizzled global source).
// ---------------------------------------------------------------------------
__global__ __launch_bounds__(256, 2)
void proj_gemm(const short* __restrict__ xb, const short* __restrict__ Wbt,
               short* __restrict__ Q, short* __restrict__ K,
               short* __restrict__ Vt) {
  __shared__ char smem[65536];
  // A0 [0,16K) A1 [16K,32K) B0 [32K,48K) B1 [48K,64K); epilogue Es reuses.
  short* Es = (short*)smem;              // epilogue [128][136]

  const int mt = blockIdx.x & 255;
  const int nt = blockIdx.x >> 8;        // 0..8
  const int wsel = nt / 3;               // 0=Q,1=K,2=V
  const int nc0 = (nt % 3) * 128;
  const int tid = threadIdx.x;
  const int wave = tid >> 6, lane = tid & 63;
  const int l15 = lane & 15, quad = lane >> 4;
  const int wm = (wave & 1) * 64, wn = (wave >> 1) * 64;

  const short* Ab = xb + (size_t)mt * 128 * CC;
  const short* Bb = Wbt + ((size_t)wsel * CC + nc0) * CC;

  // per-lane pre-swizzled source offsets (elements) for the 4 issues/wave
  int aoff[4];
  #pragma unroll
  for (int j = 0; j < 4; ++j) {
    const int lin = wave * 4096 + j * 1024 + lane * 16;  // byte in 16K tile
    const int r = lin >> 7;                              // row (128 B rows)
    const int s = (lin >> 4) & 7;                        // 16B slot
    aoff[j] = r * CC + ((s ^ (r & 7)) << 3);             // inverse swizzle
  }

  f32x4 acc[16];
  #pragma unroll
  for (int i = 0; i < 16; ++i) acc[i] = f32x4{0.f, 0.f, 0.f, 0.f};

  #pragma unroll
  for (int pc = 0; pc < 2; ++pc) {
    #pragma unroll
    for (int j = 0; j < 4; ++j)
      __builtin_amdgcn_global_load_lds(
          (const __attribute__((address_space(1))) void*)(Ab + pc * 64 + aoff[j]),
          (__attribute__((address_space(3))) void*)(smem + pc * 16384 + wave * 4096 + j * 1024), 16, 0, 0);
    #pragma unroll
    for (int j = 0; j < 4; ++j)
      __builtin_amdgcn_global_load_lds(
          (const __attribute__((address_space(1))) void*)(Bb + pc * 64 + aoff[j]),
          (__attribute__((address_space(3))) void*)(smem + 32768 + pc * 16384 + wave * 4096 + j * 1024), 16, 0, 0);
  }

  for (int kt = 0; kt < 6; ++kt) {
    const int kb = kt & 1;
    if (kt == 5) {
      asm volatile("s_waitcnt vmcnt(0)" ::: "memory");
    } else {
      asm volatile("s_waitcnt vmcnt(8)" ::: "memory");
    }
    __builtin_amdgcn_s_barrier();
    __builtin_amdgcn_sched_barrier(0);

    const char* As = smem + kb * 16384;
    const char* Bs = smem + 32768 + kb * 16384;
    #pragma unroll
    for (int ks = 0; ks < 2; ++ks) {
      bf16x8 af[4], bf[4];
      #pragma unroll
      for (int i = 0; i < 4; ++i) {
        const int ar = wm + i * 16 + l15;
        const int br = wn + i * 16 + l15;
        af[i] = *(const bf16x8*)(As + ar * 128 + (((ks * 4 + quad) ^ (ar & 7)) << 4));
        bf[i] = *(const bf16x8*)(Bs + br * 128 + (((ks * 4 + quad) ^ (br & 7)) << 4));
      }
      #pragma unroll
      for (int i = 0; i < 4; ++i)
        #pragma unroll
        for (int j = 0; j < 4; ++j)
          acc[i * 4 + j] =
              __builtin_amdgcn_mfma_f32_16x16x32_bf16(af[i], bf[j], acc[i * 4 + j], 0, 0, 0);
    }

    __builtin_amdgcn_sched_barrier(0);
    __builtin_amdgcn_s_barrier();
    if (kt + 2 < 6) {
      const int k0 = (kt + 2) * 64;
      #pragma unroll
      for (int j = 0; j < 4; ++j)
        __builtin_amdgcn_global_load_lds(
            (const __attribute__((address_space(1))) void*)(Ab + k0 + aoff[j]),
            (__attribute__((address_space(3))) void*)(smem + kb * 16384 + wave * 4096 + j * 1024), 16, 0, 0);
      #pragma unroll
      for (int j = 0; j < 4; ++j)
        __builtin_amdgcn_global_load_lds(
            (const __attribute__((address_space(1))) void*)(Bb + k0 + aoff[j]),
            (__attribute__((address_space(3))) void*)(smem + 32768 + kb * 16384 + wave * 4096 + j * 1024), 16, 0, 0);
    }
  }

  if (nt < 6) {
    short* O = (nt < 3) ? Q : K;
    const float sc = (nt < 3) ? QSC : 1.0f;
    #pragma unroll
    for (int i = 0; i < 4; ++i)
      #pragma unroll
      for (int j = 0; j < 4; ++j) {
        const f32x4 a = acc[i * 4 + j];
        const int r0 = mt * 128 + wm + i * 16 + quad * 4;
        const int c = nc0 + wn + j * 16 + l15;
        #pragma unroll
        for (int r = 0; r < 4; ++r) O[(size_t)(r0 + r) * CC + c] = f2bf(a[r] * sc);
      }
  } else {
    __syncthreads();                     // done with staging; reuse as Es
    #pragma unroll
    for (int i = 0; i < 4; ++i)
      #pragma unroll
      for (int j = 0; j < 4; ++j) {
        const f32x4 a = acc[i * 4 + j];
        const int dl = wn + j * 16 + l15;       // local col (d)
        const int ml = wm + i * 16 + quad * 4;  // local row (t)
        short4 p4;
        p4.x = f2bf(a[0]); p4.y = f2bf(a[1]); p4.z = f2bf(a[2]); p4.w = f2bf(a[3]);
        *(short4*)(Es + (size_t)dl * 136 + ml) = p4;
      }
    __syncthreads();
    const int d0 = (nt - 6) * 128;
    const int b = mt >> 4, t0 = (mt & 15) * 128;
    const int dr = tid >> 1, hf = tid & 1;
    const short* src = Es + (size_t)dr * 136 + hf * 64;
    short* dst = Vt + ((size_t)b * CC + d0 + dr) * TT + t0 + hf * 64;
    #pragma unroll
    for (int c = 0; c < 8; ++c)
      *(bf16x8*)(dst + c * 8) = *(const bf16x8*)(src + c * 8);
  }
}

// ===========================================================================
// Flash attention, causal, 64q/4-wave blocks, 32-key chunks, async
// global_load_lds phase-shifted staging (round-2 proven core).
//
// attn_split (prefix/parity-tail): pair (b,j) of co-resident blocks
// (blk, blk+256), both exactly 33 chunks:
//   role A: tile L=j FULL (2j+2 chunks, final) then EVEN tail chunks of
//           H=31-j in [2j+2, 64-2j) -> partial in OB (31-2j chunks).
//   role B: tile H prefix [0,2j+2) + ODD tail chunks -> partial in out
//           (unnormalized), 33 chunks total.
// At wall w both roles read chunk w (identical K/V during prefix -> fetch
// shared through L2) or adjacent 2w-2j-{1,2} (tail). Only 256 H-tiles are
// combined (round-5 split all 512 -> 185 MB writes; this halves partials).
// Chunk sequence unified: ck(i) = i < pivot ? i : base + 2*(i-pivot).
// ===========================================================================

#define ATTN_PRELUDE                                                          \
  __shared__ char sm[54272];                                                  \
  char* KsS = sm;                                                             \
  char* VsS = sm + 24576;                                                     \
  const int tid = threadIdx.x;                                                \
  const int wave = tid >> 6, lane = tid & 63;                                 \
  const int l15 = lane & 15, quad = lane >> 4;                                \
  short* pw = (short*)(sm + 49152) + wave * 640;                              \
  bf16x8 onesf;                                                               \
  _Pragma("unroll")                                                           \
  for (int i = 0; i < 8; ++i) onesf[i] = (short)0x3F80;                       \
  int koff[6], voff[6];                                                       \
  _Pragma("unroll")                                                           \
  for (int j = 0; j < 6; ++j) {                                               \
    const int lin = wave * 6144 + j * 1024 + lane * 16;                       \
    const int kr = lin / 768;                                                 \
    const int ksl = (lin - kr * 768) >> 4;                                    \
    koff[j] = kr * 768 + ((ksl ^ (kr & 7)) << 4);                             \
    const int vr = lin >> 6;                                                  \
    const int vsl = (lin >> 4) & 3;                                           \
    voff[j] = vr * 4096 + (((vsl - (vr >> 2)) & 3) << 4);                     \
  }                                                                           \
  char* KsW = KsS + wave * 6144;                                              \
  char* VsW = VsS + wave * 6144;

#define STAGE_K(ck)                                                           \
  do {                                                                        \
    const size_t kby_ = (size_t)(ck) * 24576;                                 \
    _Pragma("unroll")                                                         \
    for (int j5 = 0; j5 < 6; ++j5)                                            \
      __builtin_amdgcn_global_load_lds(                                       \
          (const __attribute__((address_space(1))) void*)(kbB + kby_ + koff[j5]), \
          (__attribute__((address_space(3))) void*)(KsW + j5 * 1024), 16, 0, 0);  \
  } while (0)

#define STAGE_V(ck)                                                           \
  do {                                                                        \
    const size_t vby_ = (size_t)(ck) * 64;                                    \
    _Pragma("unroll")                                                         \
    for (int j5 = 0; j5 < 6; ++j5)                                            \
      __builtin_amdgcn_global_load_lds(                                       \
          (const __attribute__((address_space(1))) void*)(vtB + vby_ + voff[j5]), \
          (__attribute__((address_space(3))) void*)(VsW + j5 * 1024), 16, 0, 0);  \
  } while (0)

__global__ __launch_bounds__(256, 2)
void attn_plain(const short* __restrict__ Q, const short* __restrict__ K,
                const short* __restrict__ Vt, float* __restrict__ out) {
  ATTN_PRELUDE
  const int blk = blockIdx.x;
  const int qt = 31 - (blk >> 4);
  const int b  = blk & 15;
  const int q0 = qt * 64 + wave * 16;

  bf16x8 qf[12];
  const short* qp = Q + ((size_t)b * TT + q0 + l15) * CC + quad * 8;
  #pragma unroll
  for (int ks = 0; ks < 12; ++ks) qf[ks] = *(const bf16x8*)(qp + ks * 32);

  f32x4 o[24];
  #pragma unroll
  for (int n = 0; n < 24; ++n) o[n] = f32x4{0.f, 0.f, 0.f, 0.f};
  f32x4 lsum = f32x4{0.f, 0.f, 0.f, 0.f};
  float m[4];
  #pragma unroll
  for (int r = 0; r < 4; ++r) m[r] = -INFINITY;

  const char* kbB = (const char*)(K + (size_t)b * TT * CC);
  const char* vtB = (const char*)(Vt + (size_t)b * CC * TT);
  const int nchunk = qt * 2 + 2;

  STAGE_K(0);
  STAGE_V(0);

  for (int kc = 0; kc < nchunk; ++kc) {
    const int k0 = kc * 32;
    asm volatile("s_waitcnt vmcnt(6)" ::: "memory");
    __builtin_amdgcn_s_barrier();
    __builtin_amdgcn_sched_barrier(0);

    f32x4 s0 = f32x4{0.f, 0.f, 0.f, 0.f};
    f32x4 s1 = f32x4{0.f, 0.f, 0.f, 0.f};
    const bool active = (k0 <= q0 + 15);
    if (active) {
      #pragma unroll
      for (int ks = 0; ks < 12; ++ks) {
        const int sl = (ks * 4 + quad) ^ (l15 & 7);
        const bf16x8 b0 = *(const bf16x8*)(KsS + l15 * 768 + (sl << 4));
        const bf16x8 b1 = *(const bf16x8*)(KsS + (16 + l15) * 768 + (sl << 4));
        s0 = __builtin_amdgcn_mfma_f32_16x16x32_bf16(qf[ks], b0, s0, 0, 0, 0);
        s1 = __builtin_amdgcn_mfma_f32_16x16x32_bf16(qf[ks], b1, s1, 0, 0, 0);
      }
    }
    __builtin_amdgcn_sched_barrier(0);
    __builtin_amdgcn_s_barrier();
    { const int kn = (kc + 1 < nchunk) ? (kc + 1) : kc; STAGE_K(kn); }
    asm volatile("s_waitcnt vmcnt(6)" ::: "memory");
    __builtin_amdgcn_s_barrier();
    __builtin_amdgcn_sched_barrier(0);

    if (active) {
      const bool domask = (k0 + 31 > q0);
      float mx[4];
      #pragma unroll
      for (int r = 0; r < 4; ++r) {
        float a = s0[r], c = s1[r];
        if (domask) {
          const int qg = q0 + quad * 4 + r;
          if (k0 + l15 > qg)      a = -INFINITY;
          if (k0 + 16 + l15 > qg) c = -INFINITY;
        }
        s0[r] = a; s1[r] = c;
        float v = fmaxf(a, c);
        v = fmaxf(v, __shfl_xor(v, 1));
        v = fmaxf(v, __shfl_xor(v, 2));
        v = fmaxf(v, __shfl_xor(v, 4));
        v = fmaxf(v, __shfl_xor(v, 8));
        mx[r] = v;
      }
      float alpha[4];
      #pragma unroll
      for (int r = 0; r < 4; ++r) {
        const float mn = fmaxf(m[r], mx[r]);
        alpha[r] = exp2f(m[r] - mn);
        m[r] = mn;
        s0[r] = exp2f(s0[r] - mn);
        s1[r] = exp2f(s1[r] - mn);
      }
      const bool need = (alpha[0] < 1.f) | (alpha[1] < 1.f) |
                        (alpha[2] < 1.f) | (alpha[3] < 1.f);
      if (__any(need)) {
        #pragma unroll
        for (int r = 0; r < 4; ++r) lsum[r] *= alpha[r];
        #pragma unroll
        for (int n = 0; n < 24; ++n) {
          #pragma unroll
          for (int r = 0; r < 4; ++r) o[n][r] *= alpha[r];
        }
      }
      #pragma unroll
      for (int r = 0; r < 4; ++r) {
        pw[(quad * 4 + r) * 40 + l15]      = f2bf(s0[r]);
        pw[(quad * 4 + r) * 40 + 16 + l15] = f2bf(s1[r]);
      }
      const bf16x8 pf = *(const bf16x8*)(pw + l15 * 40 + quad * 8);
      lsum = __builtin_amdgcn_mfma_f32_16x16x32_bf16(pf, onesf, lsum, 0, 0, 0);
      #pragma unroll
      for (int n = 0; n < 24; ++n) {
        const int vrow = n * 16 + l15;
        const bf16x8 vf = *(const bf16x8*)(VsS + vrow * 64 + (((quad + (vrow >> 2)) & 3) << 4));
        o[n] = __builtin_amdgcn_mfma_f32_16x16x32_bf16(pf, vf, o[n], 0, 0, 0);
      }
    }
    __builtin_amdgcn_sched_barrier(0);
    __builtin_amdgcn_s_barrier();
    { const int kn = (kc + 1 < nchunk) ? (kc + 1) : kc; STAGE_V(kn); }
  }

  float linv[4];
  #pragma unroll
  for (int r = 0; r < 4; ++r) linv[r] = 1.f / lsum[r];
  float* ob = out + ((size_t)b * TT + q0) * CC;
  #pragma unroll
  for (int n = 0; n < 24; ++n) {
    #pragma unroll
    for (int r = 0; r < 4; ++r) {
      ob[(size_t)(quad * 4 + r) * CC + n * 16 + l15] = o[n][r] * linv[r];
    }
  }
}

__global__ __launch_bounds__(256, 2)
void attn_split(const short* __restrict__ Q, const short* __restrict__ K,
                const short* __restrict__ Vt, float* __restrict__ out,
                float* __restrict__ OB, float* __restrict__ ML) {
  ATTN_PRELUDE
  const int blk = blockIdx.x;
  const int b = blk & 15;                   // XCD = b%8
  const int s = blk >> 4;                   // 0..31
  const int j = s & 15;
  const int role = s >> 4;                  // 0=A, 1=B
  const int p = b * 16 + j;                 // H-tile partial slot

  const char* kbB = (const char*)(K + (size_t)b * TT * CC);
  const char* vtB = (const char*)(Vt + (size_t)b * CC * TT);

  const int nph = role ? 1 : 2;
  #pragma unroll 1
  for (int ph = 0; ph < nph; ++ph) {
    int qt, count, pivot, base, mode;       // mode: 0 final, 1 ->OB, 2 ->out
    if (role == 0) {
      if (ph == 0) { qt = j;      count = 2 * j + 2;  pivot = 64;        base = 0;         mode = 0; }
      else         { qt = 31 - j; count = 31 - 2 * j; pivot = 0;         base = 2 * j + 2; mode = 1; }
    } else         { qt = 31 - j; count = 33;         pivot = 2 * j + 2; base = 2 * j + 3; mode = 2; }
    const int q0 = qt * 64 + wave * 16;

    bf16x8 qf[12];
    const short* qp = Q + ((size_t)b * TT + q0 + l15) * CC + quad * 8;
    #pragma unroll
    for (int ks = 0; ks < 12; ++ks) qf[ks] = *(const bf16x8*)(qp + ks * 32);
    // drain q loads + previous phase's trailing stages -> clean vmcnt base
    asm volatile("s_waitcnt vmcnt(0)" ::: "memory");

    f32x4 o[24];
    #pragma unroll
    for (int n = 0; n < 24; ++n) o[n] = f32x4{0.f, 0.f, 0.f, 0.f};
    f32x4 lsum = f32x4{0.f, 0.f, 0.f, 0.f};
    float m[4];
    #pragma unroll
    for (int r = 0; r < 4; ++r) m[r] = -INFINITY;

    // ck(i) = i < pivot ? i : base + 2*(i - pivot)
    const int ck0 = (0 < pivot) ? 0 : base;
    STAGE_K(ck0);
    STAGE_V(ck0);

    #pragma unroll 1
    for (int i = 0; i < count; ++i) {
      const int kc = (i < pivot) ? i : (base + 2 * (i - pivot));
      const int in = (i + 1 < count) ? (i + 1) : i;
      const int kn = (in < pivot) ? in : (base + 2 * (in - pivot));
      const int k0 = kc * 32;
      asm volatile("s_waitcnt vmcnt(6)" ::: "memory");
      __builtin_amdgcn_s_barrier();
      __builtin_amdgcn_sched_barrier(0);

      f32x4 s0 = f32x4{0.f, 0.f, 0.f, 0.f};
      f32x4 s1 = f32x4{0.f, 0.f, 0.f, 0.f};
      const bool active = (k0 <= q0 + 15);
      if (active) {
        #pragma unroll
        for (int ks = 0; ks < 12; ++ks) {
          const int sl = (ks * 4 + quad) ^ (l15 & 7);
          const bf16x8 b0 = *(const bf16x8*)(KsS + l15 * 768 + (sl << 4));
          const bf16x8 b1 = *(const bf16x8*)(KsS + (16 + l15) * 768 + (sl << 4));
          s0 = __builtin_amdgcn_mfma_f32_16x16x32_bf16(qf[ks], b0, s0, 0, 0, 0);
          s1 = __builtin_amdgcn_mfma_f32_16x16x32_bf16(qf[ks], b1, s1, 0, 0, 0);
        }
      }
      __builtin_amdgcn_sched_barrier(0);
      __builtin_amdgcn_s_barrier();
      STAGE_K(kn);
      asm volatile("s_waitcnt vmcnt(6)" ::: "memory");
      __builtin_amdgcn_s_barrier();
      __builtin_amdgcn_sched_barrier(0);

      if (active) {
        const bool domask = (k0 + 31 > q0);
        float mx[4];
        #pragma unroll
        for (int r = 0; r < 4; ++r) {
          float a = s0[r], c = s1[r];
          if (domask) {
            const int qg = q0 + quad * 4 + r;
            if (k0 + l15 > qg)      a = -INFINITY;
            if (k0 + 16 + l15 > qg) c = -INFINITY;
          }
          s0[r] = a; s1[r] = c;
          float v = fmaxf(a, c);
          v = fmaxf(v, __shfl_xor(v, 1));
          v = fmaxf(v, __shfl_xor(v, 2));
          v = fmaxf(v, __shfl_xor(v, 4));
          v = fmaxf(v, __shfl_xor(v, 8));
          mx[r] = v;
        }
        float alpha[4];
        #pragma unroll
        for (int r = 0; r < 4; ++r) {
          const float mn = fmaxf(m[r], mx[r]);
          alpha[r] = exp2f(m[r] - mn);
          m[r] = mn;
          s0[r] = exp2f(s0[r] - mn);
          s1[r] = exp2f(s1[r] - mn);
        }
        const bool need = (alpha[0] < 1.f) | (alpha[1] < 1.f) |
                          (alpha[2] < 1.f) | (alpha[3] < 1.f);
        if (__any(need)) {
          #pragma unroll
          for (int r = 0; r < 4; ++r) lsum[r] *= alpha[r];
          #pragma unroll
          for (int n = 0; n < 24; ++n) {
            #pragma unroll
            for (int r = 0; r < 4; ++r) o[n][r] *= alpha[r];
          }
        }
        #pragma unroll
        for (int r = 0; r < 4; ++r) {
          pw[(quad * 4 + r) * 40 + l15]      = f2bf(s0[r]);
          pw[(quad * 4 + r) * 40 + 16 + l15] = f2bf(s1[r]);
        }
        const bf16x8 pf = *(const bf16x8*)(pw + l15 * 40 + quad * 8);
        lsum = __builtin_amdgcn_mfma_f32_16x16x32_bf16(pf, onesf, lsum, 0, 0, 0);
        #pragma unroll
        for (int n = 0; n < 24; ++n) {
          const int vrow = n * 16 + l15;
          const bf16x8 vf = *(const bf16x8*)(VsS + vrow * 64 + (((quad + (vrow >> 2)) & 3) << 4));
          o[n] = __builtin_amdgcn_mfma_f32_16x16x32_bf16(pf, vf, o[n], 0, 0, 0);
        }
      }
      __builtin_amdgcn_sched_barrier(0);
      __builtin_amdgcn_s_barrier();
      STAGE_V(kn);
    }

    // ---- epilogue
    if (mode == 0) {
      float linv[4];
      #pragma unroll
      for (int r = 0; r < 4; ++r) linv[r] = 1.f / lsum[r];
      float* ob = out + ((size_t)b * TT + q0) * CC;
      #pragma unroll
      for (int n = 0; n < 24; ++n) {
        #pragma unroll
        for (int r = 0; r < 4; ++r)
          ob[(size_t)(quad * 4 + r) * CC + n * 16 + l15] = o[n][r] * linv[r];
      }
    } else {
      float* ob = (mode == 2)
          ? out + ((size_t)b * TT + q0) * CC
          : OB + (size_t)p * 24576 + (size_t)(wave * 16) * CC;
      #pragma unroll
      for (int n = 0; n < 24; ++n) {
        #pragma unroll
        for (int r = 0; r < 4; ++r)
          ob[(size_t)(quad * 4 + r) * CC + n * 16 + l15] = o[n][r];
      }
      if (l15 == 0) {
        // ml[0..127]: partial living in out (role B); [128..255]: in OB (A)
        float* pml = ML + (size_t)p * 256 + ((mode == 2) ? 0 : 128);
        #pragma unroll
        for (int r = 0; r < 4; ++r) {
          pml[(wave * 16 + quad * 4 + r) * 2]     = m[r];
          pml[(wave * 16 + quad * 4 + r) * 2 + 1] = lsum[r];
        }
      }
    }
  }
}

// ---------------------------------------------------------------------------
// Merge partial-in-out (role B: prefix+odd tail) with partial-in-OB (role A:
// even tail) for the 256 H-tiles. exp2f(-inf - finite) = 0 is safe; both
// partials contain >=1 active chunk for every row, so lA*sA + lB*sB > 0.
// ---------------------------------------------------------------------------
__global__ __launch_bounds__(256)
void combine(float* __restrict__ out, const float* __restrict__ OB,
             const float* __restrict__ ML) {
  const int p = blockIdx.x;                 // 0..255
  const int b = p >> 4, j = p & 15;
  const int H = 31 - j;
  const int row = threadIdx.x >> 2, seg = threadIdx.x & 3;
  const float* ml = ML + (size_t)p * 256;
  const float mA = ml[row * 2],       lA = ml[row * 2 + 1];
  const float mB = ml[128 + row * 2], lB = ml[128 + row * 2 + 1];
  const float mF = fmaxf(mA, mB);
  const float sA = exp2f(mA - mF), sB = exp2f(mB - mF);
  const float inv = 1.f / (lA * sA + lB * sB);
  const float wA = sA * inv, wB = sB * inv;
  float* pa = out + ((size_t)b * TT + H * 64 + row) * CC + seg * 96;
  const float* pb = OB + (size_t)p * 24576 + (size_t)row * CC + seg * 96;
  #pragma unroll
  for (int c = 0; c < 24; ++c) {
    float4 a = *(float4*)(pa + c * 4);
    const float4 bb = *(const float4*)(pb + c * 4);
    a.x = a.x * wA + bb.x * wB;
    a.y = a.y * wA + bb.y * wB;
    a.z = a.z * wA + bb.z * wB;
    a.w = a.w * wA + bb.w * wB;
    *(float4*)(pa + c * 4) = a;
  }
}

extern "C" void kernel_launch(void* const* d_in, const int* in_sizes, int n_in,
                              void* d_out, int out_size, void* d_ws, size_t ws_size,
                              hipStream_t stream) {
  const float* x  = (const float*)d_in[0];
  const float* Wq = (const float*)d_in[1];
  const float* Wk = (const float*)d_in[2];
  const float* Wv = (const float*)d_in[3];
  float* out = (float*)d_out;

  const size_t QS = (size_t)NB * TT * CC;     // 12.58M elems
  short* Qs = (short*)d_ws;
  short* Ks = Qs + QS;
  short* Vt = Ks + QS;                        // 75,497,472 B

  const size_t base = QS * 3 * 2;
  float* OB = (float*)((char*)d_ws + base);             // 25,165,824 B
  float* ML = (float*)((char*)d_ws + base + 25165824);  //    262,144 B
  const bool split = ws_size >= base + 25165824 + 262144;

  // bf16 W^T (0.9MB) and bf16 x (25.2MB) staged in d_out until attn
  short* Wbt = (short*)d_out;
  short* xb  = (short*)((char*)d_out + 1048576);

  hipLaunchKernelGGL(conv_wt, dim3(3 * CC), dim3(CC), 0, stream, Wq, Wk, Wv, Wbt);
  hipLaunchKernelGGL(xconv, dim3(6144), dim3(256), 0, stream, x, xb);
  hipLaunchKernelGGL(proj_gemm, dim3(256 * 9), dim3(256), 0, stream,
                     xb, Wbt, Qs, Ks, Vt);
  if (split) {
    hipLaunchKernelGGL(attn_split, dim3(512), dim3(256), 0, stream,
                       Qs, Ks, Vt, out, OB, ML);
    hipLaunchKernelGGL(combine, dim3(256), dim3(256), 0, stream, out, OB, ML);
  } else {
    hipLaunchKernelGGL(attn_plain, dim3(512), dim3(256), 0, stream,
                       Qs, Ks, Vt, out);
  }
}

// Round 7
// 303.260 us; speedup vs baseline: 1.1254x; 1.0014x over previous
//
#include <hip/hip_runtime.h>
#include <hip/hip_bf16.h>

#define NB 16
#define TT 2048
#define CC 384

typedef short bf16x8 __attribute__((ext_vector_type(8)));
typedef float f32x4 __attribute__((ext_vector_type(4)));

static __device__ __forceinline__ short f2bf(float f) {
  union { __hip_bfloat16 h; short s; } u;
  u.h = __float2bfloat16(f);
  return u.s;
}

// C^-0.5 * log2(e): folded into Q at projection time (attn works in exp2 domain)
#define QSC (0.051031036307982884f * 1.4426950408889634f)

// ---------------------------------------------------------------------------
// W[3] (fp32 [C][H]) -> Wbt (bf16 [3][n=H][k=C]) via LDS transpose.
// NEW: coalesced reads (old version read 1536B-strided columns).
// grid 36 = 3 w x 12 kgroups; block transposes 32 k-rows x 384 n.
// ---------------------------------------------------------------------------
__global__ __launch_bounds__(256)
void conv_wt(const float* __restrict__ Wq, const float* __restrict__ Wk,
             const float* __restrict__ Wv, short* __restrict__ Wbt) {
  __shared__ short ls[384][34];
  const int w = blockIdx.x / 12, kg = blockIdx.x % 12;
  const float* W = (w == 0) ? Wq : (w == 1) ? Wk : Wv;
  const int tid = threadIdx.x;
  for (int e = tid; e < 32 * 384; e += 256) {
    const int r = e / 384, c = e - r * 384;          // coalesced in c
    ls[c][r] = f2bf(W[(size_t)(kg * 32 + r) * CC + c]);
  }
  __syncthreads();
  for (int e = tid; e < 32 * 384; e += 256) {
    const int n = e >> 5, r = e & 31;                // coalesced in r
    Wbt[((size_t)w * CC + n) * CC + kg * 32 + r] = ls[n][r];
  }
}

// ---------------------------------------------------------------------------
// x (fp32 [B*T*C]) -> xb (bf16), one pass.
// ---------------------------------------------------------------------------
__global__ __launch_bounds__(256)
void xconv(const float* __restrict__ x, short* __restrict__ xb) {
  const int i = (blockIdx.x * 256 + threadIdx.x) * 8;
  const float4 a = *(const float4*)(x + i);
  const float4 c = *(const float4*)(x + i + 4);
  bf16x8 r;
  r[0] = f2bf(a.x); r[1] = f2bf(a.y); r[2] = f2bf(a.z); r[3] = f2bf(a.w);
  r[4] = f2bf(c.x); r[5] = f2bf(c.y); r[6] = f2bf(c.z); r[7] = f2bf(c.w);
  *(bf16x8*)(xb + i) = r;
}

// ---------------------------------------------------------------------------
// Fused QKV projection GEMM: [32768 x 384] bf16 x [384 x 1152] bf16.
// BK=64, 64 KB LDS double-buffer, global_load_lds 16B, counted vmcnt(8).
// NEW: XCD-chunked nt-major block remap: one XCD runs all 9 nt-tiles of a
// given mt consecutively -> A-tile (96KB) stays L2-resident, ~9x less A
// re-fetch (old mt-major spread 512 concurrent blocks across all of xb).
// ---------------------------------------------------------------------------
__global__ __launch_bounds__(256, 2)
void proj_gemm(const short* __restrict__ xb, const short* __restrict__ Wbt,
               short* __restrict__ Q, short* __restrict__ K,
               short* __restrict__ Vt) {
  __shared__ char smem[65536];
  short* Es = (short*)smem;              // epilogue [128][136]

  const int xcd = blockIdx.x & 7;
  const int idx = blockIdx.x >> 3;       // 0..287
  const int mt  = xcd * 32 + idx / 9;    // 0..255
  const int nt  = idx % 9;               // 0..8
  const int wsel = nt / 3;               // 0=Q,1=K,2=V
  const int nc0 = (nt % 3) * 128;
  const int tid = threadIdx.x;
  const int wave = tid >> 6, lane = tid & 63;
  const int l15 = lane & 15, quad = lane >> 4;
  const int wm = (wave & 1) * 64, wn = (wave >> 1) * 64;

  const short* Ab = xb + (size_t)mt * 128 * CC;
  const short* Bb = Wbt + ((size_t)wsel * CC + nc0) * CC;

  int aoff[4];
  #pragma unroll
  for (int j = 0; j < 4; ++j) {
    const int lin = wave * 4096 + j * 1024 + lane * 16;  // byte in 16K tile
    const int r = lin >> 7;                              // row (128 B rows)
    const int s = (lin >> 4) & 7;                        // 16B slot
    aoff[j] = r * CC + ((s ^ (r & 7)) << 3);             // inverse swizzle
  }

  f32x4 acc[16];
  #pragma unroll
  for (int i = 0; i < 16; ++i) acc[i] = f32x4{0.f, 0.f, 0.f, 0.f};

  #pragma unroll
  for (int pc = 0; pc < 2; ++pc) {
    #pragma unroll
    for (int j = 0; j < 4; ++j)
      __builtin_amdgcn_global_load_lds(
          (const __attribute__((address_space(1))) void*)(Ab + pc * 64 + aoff[j]),
          (__attribute__((address_space(3))) void*)(smem + pc * 16384 + wave * 4096 + j * 1024), 16, 0, 0);
    #pragma unroll
    for (int j = 0; j < 4; ++j)
      __builtin_amdgcn_global_load_lds(
          (const __attribute__((address_space(1))) void*)(Bb + pc * 64 + aoff[j]),
          (__attribute__((address_space(3))) void*)(smem + 32768 + pc * 16384 + wave * 4096 + j * 1024), 16, 0, 0);
  }

  for (int kt = 0; kt < 6; ++kt) {
    const int kb = kt & 1;
    if (kt == 5) {
      asm volatile("s_waitcnt vmcnt(0)" ::: "memory");
    } else {
      asm volatile("s_waitcnt vmcnt(8)" ::: "memory");
    }
    __builtin_amdgcn_s_barrier();
    __builtin_amdgcn_sched_barrier(0);

    const char* As = smem + kb * 16384;
    const char* Bs = smem + 32768 + kb * 16384;
    #pragma unroll
    for (int ks = 0; ks < 2; ++ks) {
      bf16x8 af[4], bf[4];
      #pragma unroll
      for (int i = 0; i < 4; ++i) {
        const int ar = wm + i * 16 + l15;
        const int br = wn + i * 16 + l15;
        af[i] = *(const bf16x8*)(As + ar * 128 + (((ks * 4 + quad) ^ (ar & 7)) << 4));
        bf[i] = *(const bf16x8*)(Bs + br * 128 + (((ks * 4 + quad) ^ (br & 7)) << 4));
      }
      #pragma unroll
      for (int i = 0; i < 4; ++i)
        #pragma unroll
        for (int j = 0; j < 4; ++j)
          acc[i * 4 + j] =
              __builtin_amdgcn_mfma_f32_16x16x32_bf16(af[i], bf[j], acc[i * 4 + j], 0, 0, 0);
    }

    __builtin_amdgcn_sched_barrier(0);
    __builtin_amdgcn_s_barrier();
    if (kt + 2 < 6) {
      const int k0 = (kt + 2) * 64;
      #pragma unroll
      for (int j = 0; j < 4; ++j)
        __builtin_amdgcn_global_load_lds(
            (const __attribute__((address_space(1))) void*)(Ab + k0 + aoff[j]),
            (__attribute__((address_space(3))) void*)(smem + kb * 16384 + wave * 4096 + j * 1024), 16, 0, 0);
      #pragma unroll
      for (int j = 0; j < 4; ++j)
        __builtin_amdgcn_global_load_lds(
            (const __attribute__((address_space(1))) void*)(Bb + k0 + aoff[j]),
            (__attribute__((address_space(3))) void*)(smem + 32768 + kb * 16384 + wave * 4096 + j * 1024), 16, 0, 0);
    }
  }

  if (nt < 6) {
    short* O = (nt < 3) ? Q : K;
    const float sc = (nt < 3) ? QSC : 1.0f;
    #pragma unroll
    for (int i = 0; i < 4; ++i)
      #pragma unroll
      for (int j = 0; j < 4; ++j) {
        const f32x4 a = acc[i * 4 + j];
        const int r0 = mt * 128 + wm + i * 16 + quad * 4;
        const int c = nc0 + wn + j * 16 + l15;
        #pragma unroll
        for (int r = 0; r < 4; ++r) O[(size_t)(r0 + r) * CC + c] = f2bf(a[r] * sc);
      }
  } else {
    __syncthreads();                     // done with staging; reuse as Es
    #pragma unroll
    for (int i = 0; i < 4; ++i)
      #pragma unroll
      for (int j = 0; j < 4; ++j) {
        const f32x4 a = acc[i * 4 + j];
        const int dl = wn + j * 16 + l15;       // local col (d)
        const int ml = wm + i * 16 + quad * 4;  // local row (t)
        short4 p4;
        p4.x = f2bf(a[0]); p4.y = f2bf(a[1]); p4.z = f2bf(a[2]); p4.w = f2bf(a[3]);
        *(short4*)(Es + (size_t)dl * 136 + ml) = p4;
      }
    __syncthreads();
    const int d0 = (nt - 6) * 128;
    const int b = mt >> 4, t0 = (mt & 15) * 128;
    const int dr = tid >> 1, hf = tid & 1;
    const short* src = Es + (size_t)dr * 136 + hf * 64;
    short* dst = Vt + ((size_t)b * CC + d0 + dr) * TT + t0 + hf * 64;
    #pragma unroll
    for (int c = 0; c < 8; ++c)
      *(bf16x8*)(dst + c * 8) = *(const bf16x8*)(src + c * 8);
  }
}

// ===========================================================================
// Flash attention, causal, 64q/4-wave blocks, 32-key chunks.
//
// attn_split (round 7): prefix/parity-tail split (round-6, balanced+local)
// PLUS V double-buffer schedule: 2 barriers + 1 vmcnt wait per chunk (was
// 4 + 2). V(i+1) staged into the alternate buffer right after the top
// barrier (overlaps QK^T); K(i+1) staged right after the QK barrier
// (overlaps softmax+PV). No post-PV barrier. LDS 78848 B, 2 blocks/CU.
// ===========================================================================

#define STAGE_K(ck)                                                           \
  do {                                                                        \
    const size_t kby_ = (size_t)(ck) * 24576;                                 \
    _Pragma("unroll")                                                         \
    for (int j5 = 0; j5 < 6; ++j5)                                            \
      __builtin_amdgcn_global_load_lds(                                       \
          (const __attribute__((address_space(1))) void*)(kbB + kby_ + koff[j5]), \
          (__attribute__((address_space(3))) void*)(KsW + j5 * 1024), 16, 0, 0);  \
  } while (0)

#define STAGE_V(ck)                                                           \
  do {                                                                        \
    const size_t vby_ = (size_t)(ck) * 64;                                    \
    _Pragma("unroll")                                                         \
    for (int j5 = 0; j5 < 6; ++j5)                                            \
      __builtin_amdgcn_global_load_lds(                                       \
          (const __attribute__((address_space(1))) void*)(vtB + vby_ + voff[j5]), \
          (__attribute__((address_space(3))) void*)(VsW + j5 * 1024), 16, 0, 0);  \
  } while (0)

// buffer-indexed V stage for the double-buffered split kernel
#define STAGE_V2(ck, buf)                                                     \
  do {                                                                        \
    const size_t vby_ = (size_t)(ck) * 64;                                    \
    char* vdst_ = sm + 24576 + (size_t)(buf) * 24576 + wave * 6144;           \
    _Pragma("unroll")                                                         \
    for (int j5 = 0; j5 < 6; ++j5)                                            \
      __builtin_amdgcn_global_load_lds(                                       \
          (const __attribute__((address_space(1))) void*)(vtB + vby_ + voff[j5]), \
          (__attribute__((address_space(3))) void*)(vdst_ + j5 * 1024), 16, 0, 0);  \
  } while (0)

// ---------------------------------------------------------------------------
// attn_plain: round-2-proven fallback (single V buffer, phase-shifted).
// Only used when ws_size is too small for the split path.
// ---------------------------------------------------------------------------
__global__ __launch_bounds__(256, 2)
void attn_plain(const short* __restrict__ Q, const short* __restrict__ K,
                const short* __restrict__ Vt, float* __restrict__ out) {
  __shared__ char sm[54272];
  char* KsS = sm;
  char* VsS = sm + 24576;
  const int tid = threadIdx.x;
  const int wave = tid >> 6, lane = tid & 63;
  const int l15 = lane & 15, quad = lane >> 4;
  short* pw = (short*)(sm + 49152) + wave * 640;
  bf16x8 onesf;
  #pragma unroll
  for (int i = 0; i < 8; ++i) onesf[i] = (short)0x3F80;
  int koff[6], voff[6];
  #pragma unroll
  for (int j = 0; j < 6; ++j) {
    const int lin = wave * 6144 + j * 1024 + lane * 16;
    const int kr = lin / 768;
    const int ksl = (lin - kr * 768) >> 4;
    koff[j] = kr * 768 + ((ksl ^ (kr & 7)) << 4);
    const int vr = lin >> 6;
    const int vsl = (lin >> 4) & 3;
    voff[j] = vr * 4096 + (((vsl - (vr >> 2)) & 3) << 4);
  }
  char* KsW = KsS + wave * 6144;
  char* VsW = VsS + wave * 6144;

  const int blk = blockIdx.x;
  const int qt = 31 - (blk >> 4);
  const int b  = blk & 15;
  const int q0 = qt * 64 + wave * 16;

  bf16x8 qf[12];
  const short* qp = Q + ((size_t)b * TT + q0 + l15) * CC + quad * 8;
  #pragma unroll
  for (int ks = 0; ks < 12; ++ks) qf[ks] = *(const bf16x8*)(qp + ks * 32);

  f32x4 o[24];
  #pragma unroll
  for (int n = 0; n < 24; ++n) o[n] = f32x4{0.f, 0.f, 0.f, 0.f};
  f32x4 lsum = f32x4{0.f, 0.f, 0.f, 0.f};
  float m[4];
  #pragma unroll
  for (int r = 0; r < 4; ++r) m[r] = -INFINITY;

  const char* kbB = (const char*)(K + (size_t)b * TT * CC);
  const char* vtB = (const char*)(Vt + (size_t)b * CC * TT);
  const int nchunk = qt * 2 + 2;

  STAGE_K(0);
  STAGE_V(0);

  for (int kc = 0; kc < nchunk; ++kc) {
    const int k0 = kc * 32;
    asm volatile("s_waitcnt vmcnt(6)" ::: "memory");
    __builtin_amdgcn_s_barrier();
    __builtin_amdgcn_sched_barrier(0);

    f32x4 s0 = f32x4{0.f, 0.f, 0.f, 0.f};
    f32x4 s1 = f32x4{0.f, 0.f, 0.f, 0.f};
    const bool active = (k0 <= q0 + 15);
    if (active) {
      #pragma unroll
      for (int ks = 0; ks < 12; ++ks) {
        const int sl = (ks * 4 + quad) ^ (l15 & 7);
        const bf16x8 b0 = *(const bf16x8*)(KsS + l15 * 768 + (sl << 4));
        const bf16x8 b1 = *(const bf16x8*)(KsS + (16 + l15) * 768 + (sl << 4));
        s0 = __builtin_amdgcn_mfma_f32_16x16x32_bf16(qf[ks], b0, s0, 0, 0, 0);
        s1 = __builtin_amdgcn_mfma_f32_16x16x32_bf16(qf[ks], b1, s1, 0, 0, 0);
      }
    }
    __builtin_amdgcn_sched_barrier(0);
    __builtin_amdgcn_s_barrier();
    { const int kn = (kc + 1 < nchunk) ? (kc + 1) : kc; STAGE_K(kn); }
    asm volatile("s_waitcnt vmcnt(6)" ::: "memory");
    __builtin_amdgcn_s_barrier();
    __builtin_amdgcn_sched_barrier(0);

    if (active) {
      const bool domask = (k0 + 31 > q0);
      float mx[4];
      #pragma unroll
      for (int r = 0; r < 4; ++r) {
        float a = s0[r], c = s1[r];
        if (domask) {
          const int qg = q0 + quad * 4 + r;
          if (k0 + l15 > qg)      a = -INFINITY;
          if (k0 + 16 + l15 > qg) c = -INFINITY;
        }
        s0[r] = a; s1[r] = c;
        float v = fmaxf(a, c);
        v = fmaxf(v, __shfl_xor(v, 1));
        v = fmaxf(v, __shfl_xor(v, 2));
        v = fmaxf(v, __shfl_xor(v, 4));
        v = fmaxf(v, __shfl_xor(v, 8));
        mx[r] = v;
      }
      float alpha[4];
      #pragma unroll
      for (int r = 0; r < 4; ++r) {
        const float mn = fmaxf(m[r], mx[r]);
        alpha[r] = exp2f(m[r] - mn);
        m[r] = mn;
        s0[r] = exp2f(s0[r] - mn);
        s1[r] = exp2f(s1[r] - mn);
      }
      const bool need = (alpha[0] < 1.f) | (alpha[1] < 1.f) |
                        (alpha[2] < 1.f) | (alpha[3] < 1.f);
      if (__any(need)) {
        #pragma unroll
        for (int r = 0; r < 4; ++r) lsum[r] *= alpha[r];
        #pragma unroll
        for (int n = 0; n < 24; ++n) {
          #pragma unroll
          for (int r = 0; r < 4; ++r) o[n][r] *= alpha[r];
        }
      }
      #pragma unroll
      for (int r = 0; r < 4; ++r) {
        pw[(quad * 4 + r) * 40 + l15]      = f2bf(s0[r]);
        pw[(quad * 4 + r) * 40 + 16 + l15] = f2bf(s1[r]);
      }
      const bf16x8 pf = *(const bf16x8*)(pw + l15 * 40 + quad * 8);
      lsum = __builtin_amdgcn_mfma_f32_16x16x32_bf16(pf, onesf, lsum, 0, 0, 0);
      #pragma unroll
      for (int n = 0; n < 24; ++n) {
        const int vrow = n * 16 + l15;
        const bf16x8 vf = *(const bf16x8*)(VsS + vrow * 64 + (((quad + (vrow >> 2)) & 3) << 4));
        o[n] = __builtin_amdgcn_mfma_f32_16x16x32_bf16(pf, vf, o[n], 0, 0, 0);
      }
    }
    __builtin_amdgcn_sched_barrier(0);
    __builtin_amdgcn_s_barrier();
    { const int kn = (kc + 1 < nchunk) ? (kc + 1) : kc; STAGE_V(kn); }
  }

  float linv[4];
  #pragma unroll
  for (int r = 0; r < 4; ++r) linv[r] = 1.f / lsum[r];
  float* ob = out + ((size_t)b * TT + q0) * CC;
  #pragma unroll
  for (int n = 0; n < 24; ++n) {
    #pragma unroll
    for (int r = 0; r < 4; ++r) {
      ob[(size_t)(quad * 4 + r) * CC + n * 16 + l15] = o[n][r] * linv[r];
    }
  }
}

__global__ __launch_bounds__(256, 2)
void attn_split(const short* __restrict__ Q, const short* __restrict__ K,
                const short* __restrict__ Vt, float* __restrict__ out,
                float* __restrict__ OB, float* __restrict__ ML) {
  __shared__ char sm[78848];
  // Ks [0,24576) | Vs0 [24576,49152) | Vs1 [49152,73728) | Ps [73728,78848)
  char* KsS = sm;
  const int tid = threadIdx.x;
  const int wave = tid >> 6, lane = tid & 63;
  const int l15 = lane & 15, quad = lane >> 4;
  short* pw = (short*)(sm + 73728) + wave * 640;
  bf16x8 onesf;
  #pragma unroll
  for (int i = 0; i < 8; ++i) onesf[i] = (short)0x3F80;
  int koff[6], voff[6];
  #pragma unroll
  for (int j = 0; j < 6; ++j) {
    const int lin = wave * 6144 + j * 1024 + lane * 16;
    const int kr = lin / 768;
    const int ksl = (lin - kr * 768) >> 4;
    koff[j] = kr * 768 + ((ksl ^ (kr & 7)) << 4);
    const int vr = lin >> 6;
    const int vsl = (lin >> 4) & 3;
    voff[j] = vr * 4096 + (((vsl - (vr >> 2)) & 3) << 4);
  }
  char* KsW = KsS + wave * 6144;

  const int blk = blockIdx.x;
  const int b = blk & 15;                   // XCD = b%8
  const int s = blk >> 4;                   // 0..31
  const int j = s & 15;
  const int role = s >> 4;                  // 0=A, 1=B
  const int p = b * 16 + j;                 // H-tile partial slot

  const char* kbB = (const char*)(K + (size_t)b * TT * CC);
  const char* vtB = (const char*)(Vt + (size_t)b * CC * TT);

  const int nph = role ? 1 : 2;
  #pragma unroll 1
  for (int ph = 0; ph < nph; ++ph) {
    int qt, count, pivot, base, mode;       // mode: 0 final, 1 ->OB, 2 ->out
    if (role == 0) {
      if (ph == 0) { qt = j;      count = 2 * j + 2;  pivot = 64;        base = 0;         mode = 0; }
      else         { qt = 31 - j; count = 31 - 2 * j; pivot = 0;         base = 2 * j + 2; mode = 1; }
    } else         { qt = 31 - j; count = 33;         pivot = 2 * j + 2; base = 2 * j + 3; mode = 2; }
    const int q0 = qt * 64 + wave * 16;

    bf16x8 qf[12];
    const short* qp = Q + ((size_t)b * TT + q0 + l15) * CC + quad * 8;
    #pragma unroll
    for (int ks = 0; ks < 12; ++ks) qf[ks] = *(const bf16x8*)(qp + ks * 32);
    // drain q loads + previous phase's epilogue stores -> clean vmcnt base
    asm volatile("s_waitcnt vmcnt(0)" ::: "memory");

    f32x4 o[24];
    #pragma unroll
    for (int n = 0; n < 24; ++n) o[n] = f32x4{0.f, 0.f, 0.f, 0.f};
    f32x4 lsum = f32x4{0.f, 0.f, 0.f, 0.f};
    float m[4];
    #pragma unroll
    for (int r = 0; r < 4; ++r) m[r] = -INFINITY;

    // ck(i) = i < pivot ? i : base + 2*(i - pivot)
    const int ck0 = (0 < pivot) ? 0 : base;
    STAGE_K(ck0);
    STAGE_V2(ck0, 0);

    #pragma unroll 1
    for (int i = 0; i < count; ++i) {
      const int kc = (i < pivot) ? i : (base + 2 * (i - pivot));
      const int k0 = kc * 32;
      const bool havenext = (i + 1 < count);
      const int in_ = havenext ? (i + 1) : i;
      const int kn = (in_ < pivot) ? in_ : (base + 2 * (in_ - pivot));

      // ---- b1: K(i), V(i) landed & visible; V[(i+1)&1] readers done
      asm volatile("s_waitcnt vmcnt(0)" ::: "memory");
      __builtin_amdgcn_s_barrier();
      __builtin_amdgcn_sched_barrier(0);
      // ---- stage V(i+1) into alternate buffer (overlaps QK^T)
      if (havenext) STAGE_V2(kn, (i + 1) & 1);

      f32x4 s0 = f32x4{0.f, 0.f, 0.f, 0.f};
      f32x4 s1 = f32x4{0.f, 0.f, 0.f, 0.f};
      const bool active = (k0 <= q0 + 15);
      if (active) {
        #pragma unroll
        for (int ks = 0; ks < 12; ++ks) {
          const int sl = (ks * 4 + quad) ^ (l15 & 7);
          const bf16x8 b0 = *(const bf16x8*)(KsS + l15 * 768 + (sl << 4));
          const bf16x8 b1 = *(const bf16x8*)(KsS + (16 + l15) * 768 + (sl << 4));
          s0 = __builtin_amdgcn_mfma_f32_16x16x32_bf16(qf[ks], b0, s0, 0, 0, 0);
          s1 = __builtin_amdgcn_mfma_f32_16x16x32_bf16(qf[ks], b1, s1, 0, 0, 0);
        }
      }
      __builtin_amdgcn_sched_barrier(0);
      __builtin_amdgcn_s_barrier();        // bQK: all waves done reading Ks
      // ---- stage K(i+1) (overlaps softmax + PV)
      if (havenext) STAGE_K(kn);

      if (active) {
        const bool domask = (k0 + 31 > q0);
        float mx[4];
        #pragma unroll
        for (int r = 0; r < 4; ++r) {
          float a = s0[r], c = s1[r];
          if (domask) {
            const int qg = q0 + quad * 4 + r;
            if (k0 + l15 > qg)      a = -INFINITY;
            if (k0 + 16 + l15 > qg) c = -INFINITY;
          }
          s0[r] = a; s1[r] = c;
          float v = fmaxf(a, c);
          v = fmaxf(v, __shfl_xor(v, 1));
          v = fmaxf(v, __shfl_xor(v, 2));
          v = fmaxf(v, __shfl_xor(v, 4));
          v = fmaxf(v, __shfl_xor(v, 8));
          mx[r] = v;
        }
        float alpha[4];
        #pragma unroll
        for (int r = 0; r < 4; ++r) {
          const float mn = fmaxf(m[r], mx[r]);
          alpha[r] = exp2f(m[r] - mn);
          m[r] = mn;
          s0[r] = exp2f(s0[r] - mn);
          s1[r] = exp2f(s1[r] - mn);
        }
        const bool need = (alpha[0] < 1.f) | (alpha[1] < 1.f) |
                          (alpha[2] < 1.f) | (alpha[3] < 1.f);
        if (__any(need)) {
          #pragma unroll
          for (int r = 0; r < 4; ++r) lsum[r] *= alpha[r];
          #pragma unroll
          for (int n = 0; n < 24; ++n) {
            #pragma unroll
            for (int r = 0; r < 4; ++r) o[n][r] *= alpha[r];
          }
        }
        #pragma unroll
        for (int r = 0; r < 4; ++r) {
          pw[(quad * 4 + r) * 40 + l15]      = f2bf(s0[r]);
          pw[(quad * 4 + r) * 40 + 16 + l15] = f2bf(s1[r]);
        }
        const bf16x8 pf = *(const bf16x8*)(pw + l15 * 40 + quad * 8);
        lsum = __builtin_amdgcn_mfma_f32_16x16x32_bf16(pf, onesf, lsum, 0, 0, 0);
        const char* Vsb = sm + 24576 + (size_t)(i & 1) * 24576;
        #pragma unroll
        for (int n = 0; n < 24; ++n) {
          const int vrow = n * 16 + l15;
          const bf16x8 vf = *(const bf16x8*)(Vsb + vrow * 64 + (((quad + (vrow >> 2)) & 3) << 4));
          o[n] = __builtin_amdgcn_mfma_f32_16x16x32_bf16(pf, vf, o[n], 0, 0, 0);
        }
      }
      // no post-PV barrier: V(i+1) goes to the alternate buffer; K(i+1)
      // staging was already ordered by bQK.
    }
    // end-of-phase: all waves must finish reads before next phase restages
    __builtin_amdgcn_s_barrier();

    // ---- epilogue
    if (mode == 0) {
      float linv[4];
      #pragma unroll
      for (int r = 0; r < 4; ++r) linv[r] = 1.f / lsum[r];
      float* ob = out + ((size_t)b * TT + q0) * CC;
      #pragma unroll
      for (int n = 0; n < 24; ++n) {
        #pragma unroll
        for (int r = 0; r < 4; ++r)
          ob[(size_t)(quad * 4 + r) * CC + n * 16 + l15] = o[n][r] * linv[r];
      }
    } else {
      float* ob = (mode == 2)
          ? out + ((size_t)b * TT + q0) * CC
          : OB + (size_t)p * 24576 + (size_t)(wave * 16) * CC;
      #pragma unroll
      for (int n = 0; n < 24; ++n) {
        #pragma unroll
        for (int r = 0; r < 4; ++r)
          ob[(size_t)(quad * 4 + r) * CC + n * 16 + l15] = o[n][r];
      }
      if (l15 == 0) {
        // ml[0..127]: partial living in out (role B); [128..255]: in OB (A)
        float* pml = ML + (size_t)p * 256 + ((mode == 2) ? 0 : 128);
        #pragma unroll
        for (int r = 0; r < 4; ++r) {
          pml[(wave * 16 + quad * 4 + r) * 2]     = m[r];
          pml[(wave * 16 + quad * 4 + r) * 2 + 1] = lsum[r];
        }
      }
    }
  }
}

// ---------------------------------------------------------------------------
// Merge partial-in-out (role B: prefix+odd tail) with partial-in-OB (role A:
// even tail) for the 256 H-tiles. Grid 512: block = (tile, row-half).
// ---------------------------------------------------------------------------
__global__ __launch_bounds__(256)
void combine(float* __restrict__ out, const float* __restrict__ OB,
             const float* __restrict__ ML) {
  const int p = blockIdx.x >> 1;            // 0..255
  const int half = blockIdx.x & 1;
  const int b = p >> 4, j = p & 15;
  const int H = 31 - j;
  const int row = half * 32 + (threadIdx.x >> 3);
  const int seg = threadIdx.x & 7;          // 8 segs x 48 floats
  const float* ml = ML + (size_t)p * 256;
  const float mA = ml[row * 2],       lA = ml[row * 2 + 1];
  const float mB = ml[128 + row * 2], lB = ml[128 + row * 2 + 1];
  const float mF = fmaxf(mA, mB);
  const float sA = exp2f(mA - mF), sB = exp2f(mB - mF);
  const float inv = 1.f / (lA * sA + lB * sB);
  const float wA = sA * inv, wB = sB * inv;
  float* pa = out + ((size_t)b * TT + H * 64 + row) * CC + seg * 48;
  const float* pb = OB + (size_t)p * 24576 + (size_t)row * CC + seg * 48;
  #pragma unroll
  for (int c = 0; c < 12; ++c) {
    float4 a = *(float4*)(pa + c * 4);
    const float4 bb = *(const float4*)(pb + c * 4);
    a.x = a.x * wA + bb.x * wB;
    a.y = a.y * wA + bb.y * wB;
    a.z = a.z * wA + bb.z * wB;
    a.w = a.w * wA + bb.w * wB;
    *(float4*)(pa + c * 4) = a;
  }
}

extern "C" void kernel_launch(void* const* d_in, const int* in_sizes, int n_in,
                              void* d_out, int out_size, void* d_ws, size_t ws_size,
                              hipStream_t stream) {
  const float* x  = (const float*)d_in[0];
  const float* Wq = (const float*)d_in[1];
  const float* Wk = (const float*)d_in[2];
  const float* Wv = (const float*)d_in[3];
  float* out = (float*)d_out;

  const size_t QS = (size_t)NB * TT * CC;     // 12.58M elems
  short* Qs = (short*)d_ws;
  short* Ks = Qs + QS;
  short* Vt = Ks + QS;                        // 75,497,472 B

  const size_t base = QS * 3 * 2;
  float* OB = (float*)((char*)d_ws + base);             // 25,165,824 B
  float* ML = (float*)((char*)d_ws + base + 25165824);  //    262,144 B
  const bool split = ws_size >= base + 25165824 + 262144;

  // bf16 W^T (0.9MB) and bf16 x (25.2MB) staged in d_out until attn
  short* Wbt = (short*)d_out;
  short* xb  = (short*)((char*)d_out + 1048576);

  hipLaunchKernelGGL(conv_wt, dim3(36), dim3(256), 0, stream, Wq, Wk, Wv, Wbt);
  hipLaunchKernelGGL(xconv, dim3(6144), dim3(256), 0, stream, x, xb);
  hipLaunchKernelGGL(proj_gemm, dim3(256 * 9), dim3(256), 0, stream,
                     xb, Wbt, Qs, Ks, Vt);
  if (split) {
    hipLaunchKernelGGL(attn_split, dim3(512), dim3(256), 0, stream,
                       Qs, Ks, Vt, out, OB, ML);
    hipLaunchKernelGGL(combine, dim3(512), dim3(256), 0, stream, out, OB, ML);
  } else {
    hipLaunchKernelGGL(attn_plain, dim3(512), dim3(256), 0, stream,
                       Qs, Ks, Vt, out);
  }
}